// Round 2
// baseline (132.719 us; speedup 1.0000x reference)
//
#include <hip/hip_runtime.h>

namespace {
constexpr int B = 8, C = 64, H = 128, W = 128;
constexpr int HW  = H * W;
constexpr int CHW = C * HW;
constexpr int TH  = 2;      // output rows per block
constexpr int NT  = 256;    // threads per block
constexpr int LROWS = TH + 2;
constexpr int LSTR  = 136;  // row stride in floats (16B-aligned rows, no read conflicts)
constexpr int COL0  = 4;    // data starts at col 4 (16B-aligned); col 3 / col 132 are zero pads
}

__global__ __launch_bounds__(NT) void cross_adj_att(
    const float* __restrict__ xs,   // x_stem
    const float* __restrict__ xx,   // x
    float* __restrict__ out)
{
    __shared__ float buf[2][LROWS][LSTR];   // double-buffered halo tile, 4352 B

    const int tid = threadIdx.x;
    const int tx  = tid & (W - 1);          // 0..127
    const int ty  = tid >> 7;               // 0..1
    const int b   = blockIdx.y;
    const int h0  = blockIdx.x * TH;
    const int h   = h0 + ty;

    // Zero entire LDS once: pad cols (3,132) and out-of-range halo rows stay 0 forever.
    for (int i = tid; i < 2 * LROWS * LSTR; i += NT)
        (&buf[0][0][0])[i] = 0.0f;

    // Staging role: threads 0..127 each load one float4 of the 4x128 halo tile.
    const int sr   = (tid >> 5) & 3;        // LDS row 0..3
    const int sq   = tid & 31;              // float4 index within row
    const int grow = h0 - 1 + sr;           // global row for LDS row sr
    const bool do_stage = (tid < 128) && (grow >= 0) && (grow < H);
    const int growc = grow < 0 ? 0 : (grow >= H ? H - 1 : grow);   // clamped for safe addr calc
    const float* sxs = xs + (size_t)b * CHW + (size_t)growc * W + 4 * sq;
    const float* sxx = xx + (size_t)b * CHW + (size_t)growc * W + 4 * sq;
    const int sdst = sr * LSTR + COL0 + 4 * sq;   // float index into one buffer

    // 9-point read offsets: LDS row ty holds global row h-1; col COL0+tx holds w=tx.
    const int bofs = ty * LSTR + COL0 + tx - 1;

    float aff[8];
#pragma unroll
    for (int k = 0; k < 8; ++k) aff[k] = 0.0f;

    __syncthreads();                         // zero-init visible
    if (do_stage)
        *(float4*)(&buf[0][0][0] + sdst) = *(const float4*)sxs;   // x_stem ch0 -> buf0
    __syncthreads();

    int cur = 0;

    // ---------------- Pass 1: affinity accumulation over channels of x_stem ----------------
#pragma unroll 2
    for (int c = 0; c < C; ++c) {
        const int nxt = cur ^ 1;
        float4 v;
        const float* nsrc = (c < C - 1) ? (sxs + (size_t)(c + 1) * HW) : sxx;  // last iter: x ch0
        if (do_stage) v = *(const float4*)nsrc;          // issue load early

        const float* p = &buf[cur][0][0] + bofs;
        const float n0 = p[0];
        const float n1 = p[1];
        const float n2 = p[2];
        const float n3 = p[LSTR];
        const float ce = p[LSTR + 1];
        const float n4 = p[LSTR + 2];
        const float n5 = p[2 * LSTR];
        const float n6 = p[2 * LSTR + 1];
        const float n7 = p[2 * LSTR + 2];
        aff[0] = fmaf(ce, n0, aff[0]);
        aff[1] = fmaf(ce, n1, aff[1]);
        aff[2] = fmaf(ce, n2, aff[2]);
        aff[3] = fmaf(ce, n3, aff[3]);
        aff[4] = fmaf(ce, n4, aff[4]);
        aff[5] = fmaf(ce, n5, aff[5]);
        aff[6] = fmaf(ce, n6, aff[6]);
        aff[7] = fmaf(ce, n7, aff[7]);

        if (do_stage) *(float4*)(&buf[nxt][0][0] + sdst) = v;   // write late (latency hidden)
        __syncthreads();
        cur = nxt;
    }

    // ---------------- Softmax over the 8 logits (registers only) ----------------
    {
        float m = aff[0];
#pragma unroll
        for (int k = 1; k < 8; ++k) m = fmaxf(m, aff[k]);
        float s = 0.0f;
#pragma unroll
        for (int k = 0; k < 8; ++k) { aff[k] = __expf(aff[k] - m); s += aff[k]; }
        const float inv = 1.0f / s;
#pragma unroll
        for (int k = 0; k < 8; ++k) aff[k] *= inv;
    }

    // ---------------- Pass 2: weighted neighbor sum over channels of x ----------------
    float* outp = out + (size_t)b * CHW + (size_t)h * W + tx;
#pragma unroll 2
    for (int c = 0; c < C; ++c) {
        const int nxt = cur ^ 1;
        float4 v;
        const bool st = do_stage && (c < C - 1);
        if (st) v = *(const float4*)(sxx + (size_t)(c + 1) * HW);

        const float* p = &buf[cur][0][0] + bofs;
        const float n0 = p[0];
        const float n1 = p[1];
        const float n2 = p[2];
        const float n3 = p[LSTR];
        const float n4 = p[LSTR + 2];
        const float n5 = p[2 * LSTR];
        const float n6 = p[2 * LSTR + 1];
        const float n7 = p[2 * LSTR + 2];
        float acc = aff[0] * n0;
        acc = fmaf(aff[1], n1, acc);
        acc = fmaf(aff[2], n2, acc);
        acc = fmaf(aff[3], n3, acc);
        acc = fmaf(aff[4], n4, acc);
        acc = fmaf(aff[5], n5, acc);
        acc = fmaf(aff[6], n6, acc);
        acc = fmaf(aff[7], n7, acc);
        outp[(size_t)c * HW] = acc;

        if (st) *(float4*)(&buf[nxt][0][0] + sdst) = v;
        __syncthreads();
        cur = nxt;
    }
}

extern "C" void kernel_launch(void* const* d_in, const int* in_sizes, int n_in,
                              void* d_out, int out_size, void* d_ws, size_t ws_size,
                              hipStream_t stream) {
    const float* xs = (const float*)d_in[0];   // x_stem
    const float* xx = (const float*)d_in[1];   // x
    float* out = (float*)d_out;
    dim3 grid(H / TH, B);
    cross_adj_att<<<grid, NT, 0, stream>>>(xs, xx, out);
}

// Round 3
// 130.050 us; speedup vs baseline: 1.0205x; 1.0205x over previous
//
#include <hip/hip_runtime.h>

namespace {
constexpr int B = 8, C = 64, H = 128, W = 128;
constexpr int HW  = H * W;
constexpr int CHW = C * HW;
constexpr int BHW = B * HW;
constexpr int CG  = 4;          // channel groups in K1
constexpr int CPG = C / CG;     // 16 channels per group
}

// ---------------- K1: affinity logits + softmax -> ws[k][b*h*w] ----------------
__global__ __launch_bounds__(256) void aff_kernel(const float* __restrict__ xs,
                                                  float* __restrict__ aff)
{
    __shared__ float part[CG][64][9];   // 9216 B, padded stride -> conflict-free

    const int tid = threadIdx.x;
    const int tx  = tid & 63;
    const int cg  = tid >> 6;
    const int w   = blockIdx.x * 64 + tx;   // blockIdx.x in 0..1
    const int h   = blockIdx.y;
    const int b   = blockIdx.z;

    const bool hm = h > 0, hp = h < H - 1, wm = w > 0, wp = w < W - 1;

    const float* pc = xs + (size_t)b * CHW + (size_t)cg * CPG * HW + (size_t)h * W + w;

    float a0 = 0, a1 = 0, a2 = 0, a3 = 0, a4 = 0, a5 = 0, a6 = 0, a7 = 0;
#pragma unroll 4
    for (int c = 0; c < CPG; ++c, pc += HW) {
        const float ce = pc[0];
        const float n0 = (hm && wm) ? pc[-W - 1] : 0.f;
        const float n1 = hm         ? pc[-W]     : 0.f;
        const float n2 = (hm && wp) ? pc[-W + 1] : 0.f;
        const float n3 = wm         ? pc[-1]     : 0.f;
        const float n4 = wp         ? pc[ 1]     : 0.f;
        const float n5 = (hp && wm) ? pc[ W - 1] : 0.f;
        const float n6 = hp         ? pc[ W]     : 0.f;
        const float n7 = (hp && wp) ? pc[ W + 1] : 0.f;
        a0 = fmaf(ce, n0, a0);
        a1 = fmaf(ce, n1, a1);
        a2 = fmaf(ce, n2, a2);
        a3 = fmaf(ce, n3, a3);
        a4 = fmaf(ce, n4, a4);
        a5 = fmaf(ce, n5, a5);
        a6 = fmaf(ce, n6, a6);
        a7 = fmaf(ce, n7, a7);
    }
    float* pp = &part[cg][tx][0];
    pp[0] = a0; pp[1] = a1; pp[2] = a2; pp[3] = a3;
    pp[4] = a4; pp[5] = a5; pp[6] = a6; pp[7] = a7;
    __syncthreads();

    if (tid < 64) {
        float v[8];
#pragma unroll
        for (int k = 0; k < 8; ++k)
            v[k] = part[0][tid][k] + part[1][tid][k] + part[2][tid][k] + part[3][tid][k];
        float m = v[0];
#pragma unroll
        for (int k = 1; k < 8; ++k) m = fmaxf(m, v[k]);
        float s = 0.f;
#pragma unroll
        for (int k = 0; k < 8; ++k) { v[k] = __expf(v[k] - m); s += v[k]; }
        const float inv = 1.f / s;
        const int pix = b * HW + h * W + (blockIdx.x * 64 + tid);
#pragma unroll
        for (int k = 0; k < 8; ++k) aff[k * BHW + pix] = v[k] * inv;
    }
}

// ---------------- K2: out[b,c,h,w] = sum_k aff[k][pix] * x_neighbor_k ----------------
__global__ __launch_bounds__(256) void apply_kernel(const float* __restrict__ xx,
                                                    const float* __restrict__ aff,
                                                    float* __restrict__ out)
{
    const int idx = blockIdx.x * 256 + threadIdx.x;   // == b*CHW + c*HW + h*W + w
    const int w = idx & (W - 1);
    const int h = (idx >> 7) & (H - 1);
    const bool hm = h > 0, hp = h < H - 1, wm = w > 0, wp = w < W - 1;

    const int b   = idx >> 20;
    const int pix = b * HW + (idx & (HW - 1));
    const float* pa = aff + pix;
    const float a0 = pa[0 * BHW];
    const float a1 = pa[1 * BHW];
    const float a2 = pa[2 * BHW];
    const float a3 = pa[3 * BHW];
    const float a4 = pa[4 * BHW];
    const float a5 = pa[5 * BHW];
    const float a6 = pa[6 * BHW];
    const float a7 = pa[7 * BHW];

    const float* px = xx + idx;
    float acc;
    acc = a0 * ((hm && wm) ? px[-W - 1] : 0.f);
    acc = fmaf(a1, hm         ? px[-W]     : 0.f, acc);
    acc = fmaf(a2, (hm && wp) ? px[-W + 1] : 0.f, acc);
    acc = fmaf(a3, wm         ? px[-1]     : 0.f, acc);
    acc = fmaf(a4, wp         ? px[ 1]     : 0.f, acc);
    acc = fmaf(a5, (hp && wm) ? px[ W - 1] : 0.f, acc);
    acc = fmaf(a6, hp         ? px[ W]     : 0.f, acc);
    acc = fmaf(a7, (hp && wp) ? px[ W + 1] : 0.f, acc);
    out[idx] = acc;
}

// ---------------- Fallback: round-1 fused kernel (used only if ws too small) ----------------
namespace fused {
constexpr int TH = 2, NT = 256, LROWS = TH + 2, LSTR = 136, COL0 = 4;
}
__global__ __launch_bounds__(fused::NT) void cross_adj_att_fused(
    const float* __restrict__ xs, const float* __restrict__ xx, float* __restrict__ out)
{
    using namespace fused;
    __shared__ float buf[2][LROWS][LSTR];
    const int tid = threadIdx.x;
    const int tx  = tid & (W - 1);
    const int ty  = tid >> 7;
    const int b   = blockIdx.y;
    const int h0  = blockIdx.x * TH;
    const int h   = h0 + ty;
    for (int i = tid; i < 2 * LROWS * LSTR; i += NT) (&buf[0][0][0])[i] = 0.0f;
    const int sr = (tid >> 5) & 3, sq = tid & 31;
    const int grow = h0 - 1 + sr;
    const bool do_stage = (tid < 128) && (grow >= 0) && (grow < H);
    const int growc = grow < 0 ? 0 : (grow >= H ? H - 1 : grow);
    const float* sxs = xs + (size_t)b * CHW + (size_t)growc * W + 4 * sq;
    const float* sxx = xx + (size_t)b * CHW + (size_t)growc * W + 4 * sq;
    const int sdst = sr * LSTR + COL0 + 4 * sq;
    const int bofs = ty * LSTR + COL0 + tx - 1;
    float aff[8];
#pragma unroll
    for (int k = 0; k < 8; ++k) aff[k] = 0.0f;
    __syncthreads();
    if (do_stage) *(float4*)(&buf[0][0][0] + sdst) = *(const float4*)sxs;
    __syncthreads();
    int cur = 0;
#pragma unroll 2
    for (int c = 0; c < C; ++c) {
        const int nxt = cur ^ 1;
        float4 v;
        const float* nsrc = (c < C - 1) ? (sxs + (size_t)(c + 1) * HW) : sxx;
        if (do_stage) v = *(const float4*)nsrc;
        const float* p = &buf[cur][0][0] + bofs;
        const float n0 = p[0], n1 = p[1], n2 = p[2], n3 = p[LSTR], ce = p[LSTR + 1],
                    n4 = p[LSTR + 2], n5 = p[2 * LSTR], n6 = p[2 * LSTR + 1], n7 = p[2 * LSTR + 2];
        aff[0] = fmaf(ce, n0, aff[0]); aff[1] = fmaf(ce, n1, aff[1]);
        aff[2] = fmaf(ce, n2, aff[2]); aff[3] = fmaf(ce, n3, aff[3]);
        aff[4] = fmaf(ce, n4, aff[4]); aff[5] = fmaf(ce, n5, aff[5]);
        aff[6] = fmaf(ce, n6, aff[6]); aff[7] = fmaf(ce, n7, aff[7]);
        if (do_stage) *(float4*)(&buf[nxt][0][0] + sdst) = v;
        __syncthreads();
        cur = nxt;
    }
    {
        float m = aff[0];
#pragma unroll
        for (int k = 1; k < 8; ++k) m = fmaxf(m, aff[k]);
        float s = 0.0f;
#pragma unroll
        for (int k = 0; k < 8; ++k) { aff[k] = __expf(aff[k] - m); s += aff[k]; }
        const float inv = 1.0f / s;
#pragma unroll
        for (int k = 0; k < 8; ++k) aff[k] *= inv;
    }
    float* outp = out + (size_t)b * CHW + (size_t)h * W + tx;
#pragma unroll 2
    for (int c = 0; c < C; ++c) {
        const int nxt = cur ^ 1;
        float4 v;
        const bool st = do_stage && (c < C - 1);
        if (st) v = *(const float4*)(sxx + (size_t)(c + 1) * HW);
        const float* p = &buf[cur][0][0] + bofs;
        const float n0 = p[0], n1 = p[1], n2 = p[2], n3 = p[LSTR],
                    n4 = p[LSTR + 2], n5 = p[2 * LSTR], n6 = p[2 * LSTR + 1], n7 = p[2 * LSTR + 2];
        float acc = aff[0] * n0;
        acc = fmaf(aff[1], n1, acc); acc = fmaf(aff[2], n2, acc);
        acc = fmaf(aff[3], n3, acc); acc = fmaf(aff[4], n4, acc);
        acc = fmaf(aff[5], n5, acc); acc = fmaf(aff[6], n6, acc);
        acc = fmaf(aff[7], n7, acc);
        outp[(size_t)c * HW] = acc;
        if (st) *(float4*)(&buf[nxt][0][0] + sdst) = v;
        __syncthreads();
        cur = nxt;
    }
}

extern "C" void kernel_launch(void* const* d_in, const int* in_sizes, int n_in,
                              void* d_out, int out_size, void* d_ws, size_t ws_size,
                              hipStream_t stream) {
    const float* xs = (const float*)d_in[0];   // x_stem
    const float* xx = (const float*)d_in[1];   // x
    float* out = (float*)d_out;

    const size_t need = (size_t)8 * BHW * sizeof(float);   // 4 MiB
    if (ws_size >= need) {
        float* aff = (float*)d_ws;
        aff_kernel<<<dim3(2, H, B), 256, 0, stream>>>(xs, aff);
        apply_kernel<<<(B * CHW) / 256, 256, 0, stream>>>(xx, aff, out);
    } else {
        dim3 grid(H / fused::TH, B);
        cross_adj_att_fused<<<grid, fused::NT, 0, stream>>>(xs, xx, out);
    }
}

// Round 5
// 127.532 us; speedup vs baseline: 1.0407x; 1.0197x over previous
//
#include <hip/hip_runtime.h>

namespace {
constexpr int B = 8, C = 64, H = 128, W = 128;
constexpr int HW  = H * W;
constexpr int CHW = C * HW;
constexpr int BHW = B * HW;
}

// ---------------- K1: affinity logits (4-way channel split) + softmax -> aff[pix][8] ----------------
__global__ __launch_bounds__(256) void aff_kernel(const float* __restrict__ xs,
                                                  float* __restrict__ aff)
{
    __shared__ float part[4][64][9];   // stride 9 -> conflict-free

    const int tid = threadIdx.x;
    const int tx  = tid & 63;
    const int cg  = tid >> 6;          // channel group 0..3 (16 ch each)
    const int w   = blockIdx.x * 64 + tx;
    const int h   = blockIdx.y;
    const int b   = blockIdx.z;

    const bool hm = h > 0, hp = h < H - 1, wm = w > 0, wp = w < W - 1;
    // clamped offsets: OOB neighbors read a valid (wrong) element, zeroed after the loop
    const int om = hm ? -W : 0;
    const int op = hp ?  W : 0;
    const int cm = wm ? -1 : 0;
    const int cp = wp ?  1 : 0;
    const int o0 = om + cm, o1 = om, o2 = om + cp, o3 = cm,
              o4 = cp, o5 = op + cm, o6 = op, o7 = op + cp;

    const float* pc = xs + (size_t)b * CHW + (size_t)cg * 16 * HW + h * W + w;

    float a0 = 0, a1 = 0, a2 = 0, a3 = 0, a4 = 0, a5 = 0, a6 = 0, a7 = 0;
#pragma unroll
    for (int c = 0; c < 16; ++c, pc += HW) {
        const float ce = pc[0];
        a0 = fmaf(ce, pc[o0], a0);
        a1 = fmaf(ce, pc[o1], a1);
        a2 = fmaf(ce, pc[o2], a2);
        a3 = fmaf(ce, pc[o3], a3);
        a4 = fmaf(ce, pc[o4], a4);
        a5 = fmaf(ce, pc[o5], a5);
        a6 = fmaf(ce, pc[o6], a6);
        a7 = fmaf(ce, pc[o7], a7);
    }
    // mask once: OOB logit must be exactly 0 (zero-pad dot product) before softmax
    a0 = (hm && wm) ? a0 : 0.f;
    a1 = hm         ? a1 : 0.f;
    a2 = (hm && wp) ? a2 : 0.f;
    a3 = wm         ? a3 : 0.f;
    a4 = wp         ? a4 : 0.f;
    a5 = (hp && wm) ? a5 : 0.f;
    a6 = hp         ? a6 : 0.f;
    a7 = (hp && wp) ? a7 : 0.f;

    float* pp = &part[cg][tx][0];
    pp[0] = a0; pp[1] = a1; pp[2] = a2; pp[3] = a3;
    pp[4] = a4; pp[5] = a5; pp[6] = a6; pp[7] = a7;
    __syncthreads();

    if (tid < 64) {
        float v[8];
#pragma unroll
        for (int k = 0; k < 8; ++k)
            v[k] = part[0][tid][k] + part[1][tid][k] + part[2][tid][k] + part[3][tid][k];
        float m = v[0];
#pragma unroll
        for (int k = 1; k < 8; ++k) m = fmaxf(m, v[k]);
        float s = 0.f;
#pragma unroll
        for (int k = 0; k < 8; ++k) { v[k] = __expf(v[k] - m); s += v[k]; }
        const float inv = 1.f / s;
        const size_t pix = (size_t)b * HW + h * W + (blockIdx.x * 64 + tid);
        float4 f0 = make_float4(v[0] * inv, v[1] * inv, v[2] * inv, v[3] * inv);
        float4 f1 = make_float4(v[4] * inv, v[5] * inv, v[6] * inv, v[7] * inv);
        *(float4*)(aff + pix * 8)     = f0;
        *(float4*)(aff + pix * 8 + 4) = f1;
    }
}

// ---------------- K2: out[b,c,h,w] = sum_k aff[pix][k] * x_nbr_k ; 4 channels/thread ----------------
__global__ __launch_bounds__(256) void apply_kernel(const float* __restrict__ xx,
                                                    const float* __restrict__ aff,
                                                    float* __restrict__ out)
{
    const int tid = threadIdx.x;
    const int w   = tid & 127;
    const int cq  = tid >> 7;                    // 0/1
    const int c0  = blockIdx.x * 8 + cq * 4;     // 4 channels per thread
    const int h   = blockIdx.y;
    const int b   = blockIdx.z;

    const bool hm = h > 0, hp = h < H - 1, wm = w > 0, wp = w < W - 1;
    const int om = hm ? -W : 0;
    const int op = hp ?  W : 0;
    const int cm = wm ? -1 : 0;
    const int cp = wp ?  1 : 0;
    const int o0 = om + cm, o1 = om, o2 = om + cp, o3 = cm,
              o4 = cp, o5 = op + cm, o6 = op, o7 = op + cp;

    const size_t pix = (size_t)b * HW + h * W + w;
    const float4 f0 = *(const float4*)(aff + pix * 8);
    const float4 f1 = *(const float4*)(aff + pix * 8 + 4);
    // zero the weights of OOB neighbors once; clamped loads then contribute 0
    const float a0 = (hm && wm) ? f0.x : 0.f;
    const float a1 = hm         ? f0.y : 0.f;
    const float a2 = (hm && wp) ? f0.z : 0.f;
    const float a3 = wm         ? f0.w : 0.f;
    const float a4 = wp         ? f1.x : 0.f;
    const float a5 = (hp && wm) ? f1.y : 0.f;
    const float a6 = hp         ? f1.z : 0.f;
    const float a7 = (hp && wp) ? f1.w : 0.f;

    const float* px = xx  + (size_t)b * CHW + (size_t)c0 * HW + h * W + w;
    float*       po = out + (size_t)b * CHW + (size_t)c0 * HW + h * W + w;
#pragma unroll
    for (int c = 0; c < 4; ++c, px += HW, po += HW) {
        float acc = a0 * px[o0];
        acc = fmaf(a1, px[o1], acc);
        acc = fmaf(a2, px[o2], acc);
        acc = fmaf(a3, px[o3], acc);
        acc = fmaf(a4, px[o4], acc);
        acc = fmaf(a5, px[o5], acc);
        acc = fmaf(a6, px[o6], acc);
        acc = fmaf(a7, px[o7], acc);
        po[0] = acc;
    }
}

extern "C" void kernel_launch(void* const* d_in, const int* in_sizes, int n_in,
                              void* d_out, int out_size, void* d_ws, size_t ws_size,
                              hipStream_t stream) {
    const float* xs = (const float*)d_in[0];   // x_stem
    const float* xx = (const float*)d_in[1];   // x
    float* out = (float*)d_out;
    float* aff = (float*)d_ws;                 // 8*BHW floats = 4 MiB (ws is 256 MiB)

    aff_kernel<<<dim3(2, H, B), 256, 0, stream>>>(xs, aff);
    apply_kernel<<<dim3(C / 8, H, B), 256, 0, stream>>>(xx, aff, out);
}